// Round 8
// baseline (430.505 us; speedup 1.0000x reference)
//
#include <hip/hip_runtime.h>
#include <math.h>

#define Nn 10000
#define NPAD 10048              /* j-padding for bf16 transposed h, mult of 64 */
#define INF_ 512
#define OUTF 64
#define ALPHA 0.2f
#define LOG2E 1.4426950408889634f

#define TI 64                   /* rows per block (one 16-row MFMA tile/wave) */
#define TJ 64                   /* j per tile (two 16x16x32 MFMA k-steps)    */
#define NTILES ((Nn + TJ - 1) / TJ)   /* 157 */
#define NIB    ((Nn + TI - 1) / TI)   /* 157 */
#define YS 6
#define TPC ((NTILES + YS - 1) / YS)  /* 27 */

typedef __attribute__((ext_vector_type(8))) short bfrag;   /* 8 bf16 = 4 VGPR */
typedef __attribute__((ext_vector_type(4))) float facc;    /* 4 f32 acc */
typedef __attribute__((ext_vector_type(4))) float f32x4;   /* native vec4 for
                                                              nontemporal ld  */

/* workspace layout (float offsets). No memsets: every consumed cell is written
   every call. hbfT pad cols [Nn,NPAD) stay poison (finite bf16) and are only
   ever multiplied by P=0. */
#define WS_S    0
#define WS_T    (Nn)
#define WS_TMAX (2*Nn)
#define WS_DEN  (2*Nn + 16)               /* float[YS][Nn]      */
#define WS_HP   (WS_DEN + YS*Nn)          /* float[YS][Nn*OUTF] */
#define WS_HBT  (WS_HP + YS*Nn*OUTF)      /* ushort[OUTF][NPAD], 16B-aligned */

__device__ __forceinline__ unsigned short f2bf(float f) {
    unsigned int u = __float_as_uint(f);
    u += 0x7fffu + ((u >> 16) & 1u);
    return (unsigned short)(u >> 16);
}
__device__ __forceinline__ unsigned int pk2(float a, float b) {
    return (unsigned int)f2bf(a) | ((unsigned int)f2bf(b) << 16);
}

/* ---- kernel 1: h = x@W; emit bf16 h^T, plus s = h@a_self, t = h@a_neighs ---- */
__global__ __launch_bounds__(256) void hgemm_kernel(
    const float* __restrict__ x, const float* __restrict__ W,
    const float* __restrict__ a_self, const float* __restrict__ a_neighs,
    unsigned short* __restrict__ hbfT, float* __restrict__ s, float* __restrict__ t)
{
    const int col  = threadIdx.x & 63;
    const int wid  = threadIdx.x >> 6;
    const int row0 = blockIdx.x * 16 + wid * 4;
    const float* x0 = x + row0 * INF_;

    float acc0 = 0.f, acc1 = 0.f, acc2 = 0.f, acc3 = 0.f;
    #pragma unroll 4
    for (int k4 = 0; k4 < INF_ / 4; ++k4) {
        const int k = k4 << 2;
        const float w0 = W[(k    ) * OUTF + col];
        const float w1 = W[(k + 1) * OUTF + col];
        const float w2 = W[(k + 2) * OUTF + col];
        const float w3 = W[(k + 3) * OUTF + col];
        const float4 xa = *(const float4*)(x0 +          k);
        const float4 xb = *(const float4*)(x0 +   INF_ + k);
        const float4 xc = *(const float4*)(x0 + 2*INF_ + k);
        const float4 xd = *(const float4*)(x0 + 3*INF_ + k);
        acc0 = fmaf(xa.x,w0, fmaf(xa.y,w1, fmaf(xa.z,w2, fmaf(xa.w,w3, acc0))));
        acc1 = fmaf(xb.x,w0, fmaf(xb.y,w1, fmaf(xb.z,w2, fmaf(xb.w,w3, acc1))));
        acc2 = fmaf(xc.x,w0, fmaf(xc.y,w1, fmaf(xc.z,w2, fmaf(xc.w,w3, acc2))));
        acc3 = fmaf(xd.x,w0, fmaf(xd.y,w1, fmaf(xd.z,w2, fmaf(xd.w,w3, acc3))));
    }
    ushort4 hb;
    hb.x = f2bf(acc0); hb.y = f2bf(acc1); hb.z = f2bf(acc2); hb.w = f2bf(acc3);
    *(ushort4*)(hbfT + (size_t)col * NPAD + row0) = hb;

    const float as = a_self[col], an = a_neighs[col];
    #define RED(ACC, U) { \
        float vs = (ACC) * as, vn = (ACC) * an; \
        _Pragma("unroll") \
        for (int d_ = 32; d_; d_ >>= 1) { vs += __shfl_xor(vs, d_); vn += __shfl_xor(vn, d_); } \
        if (col == 0) { s[row0 + (U)] = vs; t[row0 + (U)] = vn; } }
    RED(acc0, 0) RED(acc1, 1) RED(acc2, 2) RED(acc3, 3)
    #undef RED
}

/* ---- kernel 2: global max of t ---- */
__global__ __launch_bounds__(1024) void tmax_kernel(
    const float* __restrict__ t, float* __restrict__ tmax)
{
    __shared__ float red[16];
    float m = -3e38f;
    for (int i = threadIdx.x; i < Nn; i += 1024) m = fmaxf(m, t[i]);
    #pragma unroll
    for (int d = 32; d; d >>= 1) m = fmaxf(m, __shfl_xor(m, d));
    if ((threadIdx.x & 63) == 0) red[threadIdx.x >> 6] = m;
    __syncthreads();
    if (threadIdx.x < 16) {
        m = red[threadIdx.x];
        #pragma unroll
        for (int d = 8; d; d >>= 1) m = fmaxf(m, __shfl_xor(m, d));
        if (threadIdx.x == 0) *tmax = m;
    }
}

/* ---- kernel 3: fused attention — NO LDS, NO BARRIERS -----------------------
   Each wave owns one 16-row MFMA A-tile (rows i0+wv*16+l15). Per j-tile it:
   streams its adj/M granules (kq, kq+4) with non-temporal loads, computes the
   16 P values in registers (exactly the A-fragment layout), packs to bf16,
   loads 8 B-fragments straight from L2-resident h^T, and runs 8 MFMAs.
   Waves are fully independent -> pure-TLP latency hiding, zero sync. */
__global__ __launch_bounds__(256) void gat_main_kernel(
    const float* __restrict__ adj, const float* __restrict__ Mm,
    const unsigned short* __restrict__ hbfT, const float* __restrict__ sv,
    const float* __restrict__ tv, const float* __restrict__ tmaxp,
    float* __restrict__ den_part, float* __restrict__ hp_part)
{
    const int tid  = threadIdx.x;
    const int lane = tid & 63, wv = tid >> 6;
    const int l15  = lane & 15, kq = lane >> 4;
    const int i0   = blockIdx.x * TI;
    const int tlo  = blockIdx.y * TPC;
    const int thi  = min(NTILES, tlo + TPC);

    const int  row   = i0 + wv * 16 + l15;       /* this thread's P/A row */
    const bool rowok = row < Nn;
    const int  rowc  = min(row, Nn - 1);
    const float si = sv[rowc];
    const float mc = fmaxf(0.0f, si + *tmaxp) * LOG2E;
    const float* aRow = adj + (size_t)rowc * Nn;
    const float* mRow = Mm  + (size_t)rowc * Nn;

    /* B-fragment row bases: 4 col-blocks, col = cb*16 + l15 */
    const unsigned short* hB0 = hbfT + (size_t)(l15     ) * NPAD;
    const unsigned short* hB1 = hbfT + (size_t)(l15 + 16) * NPAD;
    const unsigned short* hB2 = hbfT + (size_t)(l15 + 32) * NPAD;
    const unsigned short* hB3 = hbfT + (size_t)(l15 + 48) * NPAD;

    facc acc0 = {0.f,0.f,0.f,0.f}, acc1 = {0.f,0.f,0.f,0.f};
    facc acc2 = {0.f,0.f,0.f,0.f}, acc3 = {0.f,0.f,0.f,0.f};
    float denacc = 0.0f;

    #define PC(dst, av, mv, tvv) { \
        float e_ = (si + (tvv)) * (mv); \
        float l_ = fmaxf(e_, ALPHA * e_); \
        dst = ((av) > 0.0f) ? exp2f(fmaf(l_, LOG2E, -mc)) : 0.0f; }

    for (int t = tlo; t < thi; ++t) {
        const int j0 = t * TJ;
        const int jA = j0 + kq * 8;       /* granule for MFMA k-step 0 */
        const int jB = jA + 32;           /* granule for MFMA k-step 1 */
        /* Nn % 8 == 0 -> granules are all-valid or all-OOB, never partial */
        const bool okA = jA < Nn, okB = jB < Nn;
        const int  cA  = okA ? jA : (Nn - 8);
        const int  cB  = okB ? jB : (Nn - 8);

        /* adj/M: read exactly once -> non-temporal (keep h^T hot in L2) */
        const f32x4 a0 = __builtin_nontemporal_load((const f32x4*)(aRow + cA));
        const f32x4 a1 = __builtin_nontemporal_load((const f32x4*)(aRow + cA + 4));
        const f32x4 a2 = __builtin_nontemporal_load((const f32x4*)(aRow + cB));
        const f32x4 a3 = __builtin_nontemporal_load((const f32x4*)(aRow + cB + 4));
        const f32x4 m0 = __builtin_nontemporal_load((const f32x4*)(mRow + cA));
        const f32x4 m1 = __builtin_nontemporal_load((const f32x4*)(mRow + cA + 4));
        const f32x4 m2 = __builtin_nontemporal_load((const f32x4*)(mRow + cB));
        const f32x4 m3 = __builtin_nontemporal_load((const f32x4*)(mRow + cB + 4));
        const f32x4 t0 = *(const f32x4*)(tv + cA);
        const f32x4 t1 = *(const f32x4*)(tv + cA + 4);
        const f32x4 t2 = *(const f32x4*)(tv + cB);
        const f32x4 t3 = *(const f32x4*)(tv + cB + 4);

        f32x4 p0, p1, p2, p3;
        PC(p0.x, a0.x, m0.x, t0.x); PC(p0.y, a0.y, m0.y, t0.y);
        PC(p0.z, a0.z, m0.z, t0.z); PC(p0.w, a0.w, m0.w, t0.w);
        PC(p1.x, a1.x, m1.x, t1.x); PC(p1.y, a1.y, m1.y, t1.y);
        PC(p1.z, a1.z, m1.z, t1.z); PC(p1.w, a1.w, m1.w, t1.w);
        PC(p2.x, a2.x, m2.x, t2.x); PC(p2.y, a2.y, m2.y, t2.y);
        PC(p2.z, a2.z, m2.z, t2.z); PC(p2.w, a2.w, m2.w, t2.w);
        PC(p3.x, a3.x, m3.x, t3.x); PC(p3.y, a3.y, m3.y, t3.y);
        PC(p3.z, a3.z, m3.z, t3.z); PC(p3.w, a3.w, m3.w, t3.w);
        if (!okA) { p0 = (f32x4){0.f,0.f,0.f,0.f}; p1 = p0; }
        if (!okB) { p2 = (f32x4){0.f,0.f,0.f,0.f}; p3 = p2; }

        denacc += ((p0.x + p0.y) + (p0.z + p0.w)) + ((p1.x + p1.y) + (p1.z + p1.w))
                + ((p2.x + p2.y) + (p2.z + p2.w)) + ((p3.x + p3.y) + (p3.z + p3.w));

        /* pack P -> bf16 A-fragments (in registers; A: row=l15, k=kq*8+e) */
        uint4 awA, awB;
        awA.x = pk2(p0.x, p0.y); awA.y = pk2(p0.z, p0.w);
        awA.z = pk2(p1.x, p1.y); awA.w = pk2(p1.z, p1.w);
        awB.x = pk2(p2.x, p2.y); awB.y = pk2(p2.z, p2.w);
        awB.z = pk2(p3.x, p3.y); awB.w = pk2(p3.z, p3.w);
        const bfrag afA = *(const bfrag*)&awA;
        const bfrag afB = *(const bfrag*)&awB;

        /* B-fragments direct from L2-resident h^T (16B contiguous each).
           jA/jB (not clamped) are safe: NPAD row length covers j<10048,
           pad values are finite and multiplied by P=0. */
        const bfrag b0A = *(const bfrag*)(hB0 + jA);
        const bfrag b0B = *(const bfrag*)(hB0 + jB);
        const bfrag b1A = *(const bfrag*)(hB1 + jA);
        const bfrag b1B = *(const bfrag*)(hB1 + jB);
        const bfrag b2A = *(const bfrag*)(hB2 + jA);
        const bfrag b2B = *(const bfrag*)(hB2 + jB);
        const bfrag b3A = *(const bfrag*)(hB3 + jA);
        const bfrag b3B = *(const bfrag*)(hB3 + jB);

        acc0 = __builtin_amdgcn_mfma_f32_16x16x32_bf16(afA, b0A, acc0, 0, 0, 0);
        acc1 = __builtin_amdgcn_mfma_f32_16x16x32_bf16(afA, b1A, acc1, 0, 0, 0);
        acc2 = __builtin_amdgcn_mfma_f32_16x16x32_bf16(afA, b2A, acc2, 0, 0, 0);
        acc3 = __builtin_amdgcn_mfma_f32_16x16x32_bf16(afA, b3A, acc3, 0, 0, 0);
        acc0 = __builtin_amdgcn_mfma_f32_16x16x32_bf16(afB, b0B, acc0, 0, 0, 0);
        acc1 = __builtin_amdgcn_mfma_f32_16x16x32_bf16(afB, b1B, acc1, 0, 0, 0);
        acc2 = __builtin_amdgcn_mfma_f32_16x16x32_bf16(afB, b2B, acc2, 0, 0, 0);
        acc3 = __builtin_amdgcn_mfma_f32_16x16x32_bf16(afB, b3B, acc3, 0, 0, 0);
    }
    #undef PC

    /* denominator: this thread holds granules {kq, kq+4} of its row; the row
       total lives across lanes {l15, l15+16, l15+32, l15+48} */
    denacc += __shfl_xor(denacc, 16);
    denacc += __shfl_xor(denacc, 32);
    if (rowok && kq == 0) den_part[blockIdx.y * Nn + row] = denacc;

    /* C/D layout (16x16x32): col = l15 (+cb*16), out-row = i0+wv*16+kq*4+r */
    float* hp = hp_part + (size_t)blockIdx.y * (Nn * OUTF);
    const int orow = i0 + wv * 16 + (kq << 2);
    #pragma unroll
    for (int r = 0; r < 4; ++r) {
        if (orow + r < Nn) {
            float* dst = hp + (size_t)(orow + r) * OUTF + l15;
            dst[0]  = acc0[r];
            dst[16] = acc1[r];
            dst[32] = acc2[r];
            dst[48] = acc3[r];
        }
    }
}

/* ---- kernel 4: sum YS parts, normalize, ELU -> d_out ---- */
__global__ __launch_bounds__(256) void finalize_kernel(
    const float* __restrict__ dp, const float* __restrict__ hp,
    float* __restrict__ out)
{
    const int idx = blockIdx.x * 256 + threadIdx.x;
    const int S = Nn * OUTF;
    const int row = idx >> 6;
    float num = 0.0f, den = 0.0f;
    #pragma unroll
    for (int y = 0; y < YS; ++y) {
        num += hp[(size_t)y * S + idx];
        den += dp[y * Nn + row];
    }
    const float v = num / den;
    out[idx] = (v > 0.0f) ? v : expm1f(v);
}

extern "C" void kernel_launch(void* const* d_in, const int* in_sizes, int n_in,
                              void* d_out, int out_size, void* d_ws, size_t ws_size,
                              hipStream_t stream) {
    const float* x        = (const float*)d_in[0];
    const float* adj      = (const float*)d_in[1];
    const float* Mm       = (const float*)d_in[2];
    const float* W        = (const float*)d_in[3];
    const float* a_self   = (const float*)d_in[4];
    const float* a_neighs = (const float*)d_in[5];

    float* out  = (float*)d_out;
    float* ws   = (float*)d_ws;
    float* s    = ws + WS_S;
    float* t    = ws + WS_T;
    float* tmax = ws + WS_TMAX;
    float* denp = ws + WS_DEN;
    float* hpp  = ws + WS_HP;
    unsigned short* hbfT = (unsigned short*)(ws + WS_HBT);

    hgemm_kernel<<<Nn / 16, 256, 0, stream>>>(x, W, a_self, a_neighs, hbfT, s, t);
    tmax_kernel<<<1, 1024, 0, stream>>>(t, tmax);
    gat_main_kernel<<<dim3(NIB, YS), 256, 0, stream>>>(
        adj, Mm, hbfT, s, t, tmax, denp, hpp);
    finalize_kernel<<<(Nn * OUTF) / 256, 256, 0, stream>>>(denp, hpp, out);
}

// Round 9
// 388.075 us; speedup vs baseline: 1.1093x; 1.1093x over previous
//
#include <hip/hip_runtime.h>
#include <math.h>

#define Nn 10000
#define NPAD 10112              /* j-padding for bf16 h^T: covers tail B reads */
#define INF_ 512
#define OUTF 64
#define ALPHA 0.2f
#define LOG2E 1.4426950408889634f

#define TI 64                   /* rows per block (16 rows per wave) */
#define TJ 128                  /* j per tile (four 16x16x32 k-steps) */
#define NT2 ((Nn + TJ - 1) / TJ)      /* 79 */
#define NIB ((Nn + TI - 1) / TI)      /* 157 */
#define YS 6
#define TPC ((NT2 + YS - 1) / YS)     /* 14 */

typedef __attribute__((ext_vector_type(8))) short bfrag;   /* 8 bf16 = 4 VGPR */
typedef __attribute__((ext_vector_type(4))) float facc;    /* 4 f32 acc */
typedef __attribute__((ext_vector_type(4))) float f32x4;   /* native vec4 */

/* workspace layout (float offsets). No memsets: every consumed cell is written
   every call. hbfT pad rows [Nn,NPAD) stay poison (finite bf16) and are only
   ever multiplied by P=0. */
#define WS_S    0
#define WS_T    (Nn)
#define WS_TMAX (2*Nn)
#define WS_DEN  (2*Nn + 16)               /* float[YS][Nn]      */
#define WS_HP   (WS_DEN + YS*Nn)          /* float[YS][Nn*OUTF] */
#define WS_HBT  (WS_HP + YS*Nn*OUTF)      /* ushort[OUTF][NPAD], 16B-aligned */

__device__ __forceinline__ unsigned short f2bf(float f) {
    unsigned int u = __float_as_uint(f);
    u += 0x7fffu + ((u >> 16) & 1u);
    return (unsigned short)(u >> 16);
}
__device__ __forceinline__ unsigned int pk2(float a, float b) {
    return (unsigned int)f2bf(a) | ((unsigned int)f2bf(b) << 16);
}

/* ---- kernel 1: h = x@W; emit bf16 h^T, plus s = h@a_self, t = h@a_neighs ---- */
__global__ __launch_bounds__(256) void hgemm_kernel(
    const float* __restrict__ x, const float* __restrict__ W,
    const float* __restrict__ a_self, const float* __restrict__ a_neighs,
    unsigned short* __restrict__ hbfT, float* __restrict__ s, float* __restrict__ t)
{
    const int col  = threadIdx.x & 63;
    const int wid  = threadIdx.x >> 6;
    const int row0 = blockIdx.x * 16 + wid * 4;
    const float* x0 = x + row0 * INF_;

    float acc0 = 0.f, acc1 = 0.f, acc2 = 0.f, acc3 = 0.f;
    #pragma unroll 4
    for (int k4 = 0; k4 < INF_ / 4; ++k4) {
        const int k = k4 << 2;
        const float w0 = W[(k    ) * OUTF + col];
        const float w1 = W[(k + 1) * OUTF + col];
        const float w2 = W[(k + 2) * OUTF + col];
        const float w3 = W[(k + 3) * OUTF + col];
        const float4 xa = *(const float4*)(x0 +          k);
        const float4 xb = *(const float4*)(x0 +   INF_ + k);
        const float4 xc = *(const float4*)(x0 + 2*INF_ + k);
        const float4 xd = *(const float4*)(x0 + 3*INF_ + k);
        acc0 = fmaf(xa.x,w0, fmaf(xa.y,w1, fmaf(xa.z,w2, fmaf(xa.w,w3, acc0))));
        acc1 = fmaf(xb.x,w0, fmaf(xb.y,w1, fmaf(xb.z,w2, fmaf(xb.w,w3, acc1))));
        acc2 = fmaf(xc.x,w0, fmaf(xc.y,w1, fmaf(xc.z,w2, fmaf(xc.w,w3, acc2))));
        acc3 = fmaf(xd.x,w0, fmaf(xd.y,w1, fmaf(xd.z,w2, fmaf(xd.w,w3, acc3))));
    }
    ushort4 hb;
    hb.x = f2bf(acc0); hb.y = f2bf(acc1); hb.z = f2bf(acc2); hb.w = f2bf(acc3);
    *(ushort4*)(hbfT + (size_t)col * NPAD + row0) = hb;

    const float as = a_self[col], an = a_neighs[col];
    #define RED(ACC, U) { \
        float vs = (ACC) * as, vn = (ACC) * an; \
        _Pragma("unroll") \
        for (int d_ = 32; d_; d_ >>= 1) { vs += __shfl_xor(vs, d_); vn += __shfl_xor(vn, d_); } \
        if (col == 0) { s[row0 + (U)] = vs; t[row0 + (U)] = vn; } }
    RED(acc0, 0) RED(acc1, 1) RED(acc2, 2) RED(acc3, 3)
    #undef RED
}

/* ---- kernel 2: global max of t ---- */
__global__ __launch_bounds__(1024) void tmax_kernel(
    const float* __restrict__ t, float* __restrict__ tmax)
{
    __shared__ float red[16];
    float m = -3e38f;
    for (int i = threadIdx.x; i < Nn; i += 1024) m = fmaxf(m, t[i]);
    #pragma unroll
    for (int d = 32; d; d >>= 1) m = fmaxf(m, __shfl_xor(m, d));
    if ((threadIdx.x & 63) == 0) red[threadIdx.x >> 6] = m;
    __syncthreads();
    if (threadIdx.x < 16) {
        m = red[threadIdx.x];
        #pragma unroll
        for (int d = 8; d; d >>= 1) m = fmaxf(m, __shfl_xor(m, d));
        if (threadIdx.x == 0) *tmax = m;
    }
}

/* ---- kernel 3: fused attention — NO LDS, raw per-tile barrier --------------
   Each wave owns one 16-row A-tile. Per 128-j tile: 4 granule-groups of
   adj/M/t loads (24 f32x4 in flight -> ~2x memory ILP, 512B/row contiguous),
   P in registers (A-fragment layout), raw s_barrier to sync the 4 waves so
   their IDENTICAL B-fragment loads hit L1, then 16 MFMAs. */
__global__ __launch_bounds__(256) void gat_main_kernel(
    const float* __restrict__ adj, const float* __restrict__ Mm,
    const unsigned short* __restrict__ hbfT, const float* __restrict__ sv,
    const float* __restrict__ tv, const float* __restrict__ tmaxp,
    float* __restrict__ den_part, float* __restrict__ hp_part)
{
    const int tid  = threadIdx.x;
    const int lane = tid & 63, wv = tid >> 6;
    const int l15  = lane & 15, kq = lane >> 4;
    const int i0   = blockIdx.x * TI;
    const int tlo  = blockIdx.y * TPC;
    const int thi  = min(NT2, tlo + TPC);

    const int  row   = i0 + wv * 16 + l15;
    const bool rowok = row < Nn;
    const int  rowc  = min(row, Nn - 1);
    const float si = sv[rowc];
    const float mc = fmaxf(0.0f, si + *tmaxp) * LOG2E;
    const float* aRow = adj + (size_t)rowc * Nn;
    const float* mRow = Mm  + (size_t)rowc * Nn;

    const unsigned short* hB0 = hbfT + (size_t)(l15     ) * NPAD;
    const unsigned short* hB1 = hbfT + (size_t)(l15 + 16) * NPAD;
    const unsigned short* hB2 = hbfT + (size_t)(l15 + 32) * NPAD;
    const unsigned short* hB3 = hbfT + (size_t)(l15 + 48) * NPAD;

    facc acc0 = {0.f,0.f,0.f,0.f}, acc1 = {0.f,0.f,0.f,0.f};
    facc acc2 = {0.f,0.f,0.f,0.f}, acc3 = {0.f,0.f,0.f,0.f};
    float denacc = 0.0f;

    #define PC(dst, av, mv, tvv) { \
        float e_ = (si + (tvv)) * (mv); \
        float l_ = fmaxf(e_, ALPHA * e_); \
        dst = ((av) > 0.0f) ? exp2f(fmaf(l_, LOG2E, -mc)) : 0.0f; }

    for (int t = tlo; t < thi; ++t) {
        const int j0 = t * TJ;
        /* granule g covers k-step g: j = j0 + g*32 + kq*8 .. +7 */
        const int jg0 = j0 +       kq * 8;
        const int jg1 = j0 + 32  + kq * 8;
        const int jg2 = j0 + 64  + kq * 8;
        const int jg3 = j0 + 96  + kq * 8;
        const bool ok0 = jg0 < Nn, ok1 = jg1 < Nn, ok2 = jg2 < Nn, ok3 = jg3 < Nn;
        const int  c0 = ok0 ? jg0 : (Nn - 8);
        const int  c1 = ok1 ? jg1 : (Nn - 8);
        const int  c2 = ok2 ? jg2 : (Nn - 8);
        const int  c3 = ok3 ? jg3 : (Nn - 8);

        /* ---- issue all adj/M/t loads for the whole 128-j tile ---- */
        #define NTL(p) __builtin_nontemporal_load((const f32x4*)(p))
        const f32x4 a00 = NTL(aRow + c0), a01 = NTL(aRow + c0 + 4);
        const f32x4 a10 = NTL(aRow + c1), a11 = NTL(aRow + c1 + 4);
        const f32x4 a20 = NTL(aRow + c2), a21 = NTL(aRow + c2 + 4);
        const f32x4 a30 = NTL(aRow + c3), a31 = NTL(aRow + c3 + 4);
        const f32x4 m00 = NTL(mRow + c0), m01 = NTL(mRow + c0 + 4);
        const f32x4 m10 = NTL(mRow + c1), m11 = NTL(mRow + c1 + 4);
        const f32x4 m20 = NTL(mRow + c2), m21 = NTL(mRow + c2 + 4);
        const f32x4 m30 = NTL(mRow + c3), m31 = NTL(mRow + c3 + 4);
        #undef NTL
        const f32x4 t00 = *(const f32x4*)(tv + c0), t01 = *(const f32x4*)(tv + c0 + 4);
        const f32x4 t10 = *(const f32x4*)(tv + c1), t11 = *(const f32x4*)(tv + c1 + 4);
        const f32x4 t20 = *(const f32x4*)(tv + c2), t21 = *(const f32x4*)(tv + c2 + 4);
        const f32x4 t30 = *(const f32x4*)(tv + c3), t31 = *(const f32x4*)(tv + c3 + 4);

        /* ---- P in registers, pack to A-fragments ---- */
        f32x4 p0, p1, p2, p3, p4, p5, p6, p7;
        PC(p0.x,a00.x,m00.x,t00.x); PC(p0.y,a00.y,m00.y,t00.y);
        PC(p0.z,a00.z,m00.z,t00.z); PC(p0.w,a00.w,m00.w,t00.w);
        PC(p1.x,a01.x,m01.x,t01.x); PC(p1.y,a01.y,m01.y,t01.y);
        PC(p1.z,a01.z,m01.z,t01.z); PC(p1.w,a01.w,m01.w,t01.w);
        PC(p2.x,a10.x,m10.x,t10.x); PC(p2.y,a10.y,m10.y,t10.y);
        PC(p2.z,a10.z,m10.z,t10.z); PC(p2.w,a10.w,m10.w,t10.w);
        PC(p3.x,a11.x,m11.x,t11.x); PC(p3.y,a11.y,m11.y,t11.y);
        PC(p3.z,a11.z,m11.z,t11.z); PC(p3.w,a11.w,m11.w,t11.w);
        PC(p4.x,a20.x,m20.x,t20.x); PC(p4.y,a20.y,m20.y,t20.y);
        PC(p4.z,a20.z,m20.z,t20.z); PC(p4.w,a20.w,m20.w,t20.w);
        PC(p5.x,a21.x,m21.x,t21.x); PC(p5.y,a21.y,m21.y,t21.y);
        PC(p5.z,a21.z,m21.z,t21.z); PC(p5.w,a21.w,m21.w,t21.w);
        PC(p6.x,a30.x,m30.x,t30.x); PC(p6.y,a30.y,m30.y,t30.y);
        PC(p6.z,a30.z,m30.z,t30.z); PC(p6.w,a30.w,m30.w,t30.w);
        PC(p7.x,a31.x,m31.x,t31.x); PC(p7.y,a31.y,m31.y,t31.y);
        PC(p7.z,a31.z,m31.z,t31.z); PC(p7.w,a31.w,m31.w,t31.w);

        const f32x4 z = {0.f,0.f,0.f,0.f};
        if (!ok0) { p0 = z; p1 = z; }
        if (!ok1) { p2 = z; p3 = z; }
        if (!ok2) { p4 = z; p5 = z; }
        if (!ok3) { p6 = z; p7 = z; }

        denacc += ((p0.x+p0.y)+(p0.z+p0.w)) + ((p1.x+p1.y)+(p1.z+p1.w))
                + ((p2.x+p2.y)+(p2.z+p2.w)) + ((p3.x+p3.y)+(p3.z+p3.w))
                + ((p4.x+p4.y)+(p4.z+p4.w)) + ((p5.x+p5.y)+(p5.z+p5.w))
                + ((p6.x+p6.y)+(p6.z+p6.w)) + ((p7.x+p7.y)+(p7.z+p7.w));

        uint4 w0, w1, w2, w3;
        w0.x = pk2(p0.x,p0.y); w0.y = pk2(p0.z,p0.w);
        w0.z = pk2(p1.x,p1.y); w0.w = pk2(p1.z,p1.w);
        w1.x = pk2(p2.x,p2.y); w1.y = pk2(p2.z,p2.w);
        w1.z = pk2(p3.x,p3.y); w1.w = pk2(p3.z,p3.w);
        w2.x = pk2(p4.x,p4.y); w2.y = pk2(p4.z,p4.w);
        w2.z = pk2(p5.x,p5.y); w2.w = pk2(p5.z,p5.w);
        w3.x = pk2(p6.x,p6.y); w3.y = pk2(p6.z,p6.w);
        w3.z = pk2(p7.x,p7.y); w3.w = pk2(p7.z,p7.w);
        const bfrag afA = *(const bfrag*)&w0;
        const bfrag afB = *(const bfrag*)&w1;
        const bfrag afC = *(const bfrag*)&w2;
        const bfrag afD = *(const bfrag*)&w3;

        /* sync the 4 waves so their identical B loads share L1 (raw barrier:
           no LDS in kernel -> no waitcnt drain attached) */
        __builtin_amdgcn_s_barrier();

        /* ---- B-fragments straight from h^T (L1/L2), 16 MFMAs ---- */
        #define KSTEP(AF, JG) { \
            const bfrag b0 = *(const bfrag*)(hB0 + (JG)); \
            const bfrag b1 = *(const bfrag*)(hB1 + (JG)); \
            const bfrag b2 = *(const bfrag*)(hB2 + (JG)); \
            const bfrag b3 = *(const bfrag*)(hB3 + (JG)); \
            acc0 = __builtin_amdgcn_mfma_f32_16x16x32_bf16(AF, b0, acc0, 0, 0, 0); \
            acc1 = __builtin_amdgcn_mfma_f32_16x16x32_bf16(AF, b1, acc1, 0, 0, 0); \
            acc2 = __builtin_amdgcn_mfma_f32_16x16x32_bf16(AF, b2, acc2, 0, 0, 0); \
            acc3 = __builtin_amdgcn_mfma_f32_16x16x32_bf16(AF, b3, acc3, 0, 0, 0); }
        KSTEP(afA, jg0)
        KSTEP(afB, jg1)
        KSTEP(afC, jg2)
        KSTEP(afD, jg3)
        #undef KSTEP
    }
    #undef PC

    /* denominator: kq lanes hold disjoint j-subsets of row l15 */
    denacc += __shfl_xor(denacc, 16);
    denacc += __shfl_xor(denacc, 32);
    if (rowok && kq == 0) den_part[blockIdx.y * Nn + row] = denacc;

    /* C/D layout (16x16x32): col = l15 (+cb*16), out-row = i0+wv*16+kq*4+r */
    float* hp = hp_part + (size_t)blockIdx.y * (Nn * OUTF);
    const int orow = i0 + wv * 16 + (kq << 2);
    #pragma unroll
    for (int r = 0; r < 4; ++r) {
        if (orow + r < Nn) {
            float* dst = hp + (size_t)(orow + r) * OUTF + l15;
            dst[0]  = acc0[r];
            dst[16] = acc1[r];
            dst[32] = acc2[r];
            dst[48] = acc3[r];
        }
    }
}

/* ---- kernel 4: sum YS parts, normalize, ELU -> d_out ---- */
__global__ __launch_bounds__(256) void finalize_kernel(
    const float* __restrict__ dp, const float* __restrict__ hp,
    float* __restrict__ out)
{
    const int idx = blockIdx.x * 256 + threadIdx.x;
    const int S = Nn * OUTF;
    const int row = idx >> 6;
    float num = 0.0f, den = 0.0f;
    #pragma unroll
    for (int y = 0; y < YS; ++y) {
        num += hp[(size_t)y * S + idx];
        den += dp[y * Nn + row];
    }
    const float v = num / den;
    out[idx] = (v > 0.0f) ? v : expm1f(v);
}

extern "C" void kernel_launch(void* const* d_in, const int* in_sizes, int n_in,
                              void* d_out, int out_size, void* d_ws, size_t ws_size,
                              hipStream_t stream) {
    const float* x        = (const float*)d_in[0];
    const float* adj      = (const float*)d_in[1];
    const float* Mm       = (const float*)d_in[2];
    const float* W        = (const float*)d_in[3];
    const float* a_self   = (const float*)d_in[4];
    const float* a_neighs = (const float*)d_in[5];

    float* out  = (float*)d_out;
    float* ws   = (float*)d_ws;
    float* s    = ws + WS_S;
    float* t    = ws + WS_T;
    float* tmax = ws + WS_TMAX;
    float* denp = ws + WS_DEN;
    float* hpp  = ws + WS_HP;
    unsigned short* hbfT = (unsigned short*)(ws + WS_HBT);

    hgemm_kernel<<<Nn / 16, 256, 0, stream>>>(x, W, a_self, a_neighs, hbfT, s, t);
    tmax_kernel<<<1, 1024, 0, stream>>>(t, tmax);
    gat_main_kernel<<<dim3(NIB, YS), 256, 0, stream>>>(
        adj, Mm, hbfT, s, t, tmax, denp, hpp);
    finalize_kernel<<<(Nn * OUTF) / 256, 256, 0, stream>>>(denp, hpp, out);
}

// Round 10
// 263.055 us; speedup vs baseline: 1.6366x; 1.4753x over previous
//
#include <hip/hip_runtime.h>
#include <math.h>

#define Nn 10000
#define NPAD 10048              /* j-padding for bf16 transposed h, mult of 64 */
#define INF_ 512
#define OUTF 64
#define ALPHA 0.2f
#define LOG2E 1.4426950408889634f

#define TI 32
#define TJ 64
#define NTILES ((Nn + TJ - 1) / TJ)   /* 157 */
#define YS 8
#define TPC ((NTILES + YS - 1) / YS)  /* 20 */

typedef __attribute__((ext_vector_type(8))) short bfrag;   /* 8 bf16 = 4 VGPR */
typedef __attribute__((ext_vector_type(4))) float facc;    /* 4 f32 acc */

/* workspace layout (float offsets). No memsets: every cell finalize consumes
   is written every call. hbfT pad cols [Nn,NPAD) stay poison (finite bf16)
   and are only ever multiplied by P=0 in the MFMA. */
#define WS_S    0
#define WS_T    (Nn)
#define WS_TMAX (2*Nn)
#define WS_DEN  (2*Nn + 16)               /* float[YS][Nn]      */
#define WS_HP   (WS_DEN + YS*Nn)          /* float[YS][Nn*OUTF] */
#define WS_HBT  (WS_HP + YS*Nn*OUTF)      /* ushort[OUTF][NPAD], 16B-aligned */

__device__ __forceinline__ unsigned short f2bf(float f) {
    unsigned int u = __float_as_uint(f);
    u += 0x7fffu + ((u >> 16) & 1u);
    return (unsigned short)(u >> 16);
}
__device__ __forceinline__ unsigned int pk2(float a, float b) {
    return (unsigned int)f2bf(a) | ((unsigned int)f2bf(b) << 16);
}

/* ---- kernel 1: h = x@W; emit bf16 h^T, plus s = h@a_self, t = h@a_neighs ---- */
__global__ __launch_bounds__(256) void hgemm_kernel(
    const float* __restrict__ x, const float* __restrict__ W,
    const float* __restrict__ a_self, const float* __restrict__ a_neighs,
    unsigned short* __restrict__ hbfT, float* __restrict__ s, float* __restrict__ t)
{
    const int col  = threadIdx.x & 63;
    const int wid  = threadIdx.x >> 6;
    const int row0 = blockIdx.x * 16 + wid * 4;
    const float* x0 = x + row0 * INF_;

    float acc0 = 0.f, acc1 = 0.f, acc2 = 0.f, acc3 = 0.f;
    #pragma unroll 4
    for (int k4 = 0; k4 < INF_ / 4; ++k4) {
        const int k = k4 << 2;
        const float w0 = W[(k    ) * OUTF + col];
        const float w1 = W[(k + 1) * OUTF + col];
        const float w2 = W[(k + 2) * OUTF + col];
        const float w3 = W[(k + 3) * OUTF + col];
        const float4 xa = *(const float4*)(x0 +          k);
        const float4 xb = *(const float4*)(x0 +   INF_ + k);
        const float4 xc = *(const float4*)(x0 + 2*INF_ + k);
        const float4 xd = *(const float4*)(x0 + 3*INF_ + k);
        acc0 = fmaf(xa.x,w0, fmaf(xa.y,w1, fmaf(xa.z,w2, fmaf(xa.w,w3, acc0))));
        acc1 = fmaf(xb.x,w0, fmaf(xb.y,w1, fmaf(xb.z,w2, fmaf(xb.w,w3, acc1))));
        acc2 = fmaf(xc.x,w0, fmaf(xc.y,w1, fmaf(xc.z,w2, fmaf(xc.w,w3, acc2))));
        acc3 = fmaf(xd.x,w0, fmaf(xd.y,w1, fmaf(xd.z,w2, fmaf(xd.w,w3, acc3))));
    }
    ushort4 hb;
    hb.x = f2bf(acc0); hb.y = f2bf(acc1); hb.z = f2bf(acc2); hb.w = f2bf(acc3);
    *(ushort4*)(hbfT + (size_t)col * NPAD + row0) = hb;

    const float as = a_self[col], an = a_neighs[col];
    #define RED(ACC, U) { \
        float vs = (ACC) * as, vn = (ACC) * an; \
        _Pragma("unroll") \
        for (int d_ = 32; d_; d_ >>= 1) { vs += __shfl_xor(vs, d_); vn += __shfl_xor(vn, d_); } \
        if (col == 0) { s[row0 + (U)] = vs; t[row0 + (U)] = vn; } }
    RED(acc0, 0) RED(acc1, 1) RED(acc2, 2) RED(acc3, 3)
    #undef RED
}

/* ---- kernel 2: global max of t ---- */
__global__ __launch_bounds__(1024) void tmax_kernel(
    const float* __restrict__ t, float* __restrict__ tmax)
{
    __shared__ float red[16];
    float m = -3e38f;
    for (int i = threadIdx.x; i < Nn; i += 1024) m = fmaxf(m, t[i]);
    #pragma unroll
    for (int d = 32; d; d >>= 1) m = fmaxf(m, __shfl_xor(m, d));
    if ((threadIdx.x & 63) == 0) red[threadIdx.x >> 6] = m;
    __syncthreads();
    if (threadIdx.x < 16) {
        m = red[threadIdx.x];
        #pragma unroll
        for (int d = 8; d; d >>= 1) m = fmaxf(m, __shfl_xor(m, d));
        if (threadIdx.x == 0) *tmax = m;
    }
}

/* ---- kernel 3: fused attention, PV via bf16 MFMA ---------------------------
   EXACT round-2 tile loop (2 barriers/tile, single LDS buffer, depth-1 reg
   prefetch — the codegen that keeps loads live, VGPR~72). Only the epilogue
   differs: partitioned per-y outputs (plain stores, no atomics/memsets),
   and YS=8 for ~4 resident blocks/CU of TLP. */
__global__ __launch_bounds__(256, 4) void gat_main_kernel(
    const float* __restrict__ adj, const float* __restrict__ Mm,
    const unsigned short* __restrict__ hbfT, const float* __restrict__ sv,
    const float* __restrict__ tv, const float* __restrict__ tmaxp,
    float* __restrict__ den_part, float* __restrict__ hp_part)
{
    __shared__ __align__(16) unsigned short hTl[OUTF][TJ + 8];  /* 9216 B */
    __shared__ __align__(16) unsigned short Pl[TI][TJ + 8];     /* 4608 B */

    const int tid = threadIdx.x;
    const int i0  = blockIdx.x * TI;
    const int tlo = blockIdx.y * TPC;
    const int thi = min(NTILES, tlo + TPC);

    /* P-compute mapping: 32 rows x 8 j-granules */
    const int rr = tid >> 3, jc = tid & 7;
    const int prow = i0 + rr;
    const bool rowok = prow < Nn;
    const float si = rowok ? sv[prow] : 0.0f;
    const float mc = fmaxf(0.0f, si + *tmaxp) * LOG2E;
    const float* aRow = adj + (size_t)prow * Nn;
    const float* mRow = Mm  + (size_t)prow * Nn;

    /* h-stage mapping: 64 cols x 4 segments of 16 j */
    const int hc_ = tid >> 2, hseg = tid & 3;
    const unsigned short* hsrc = hbfT + (size_t)hc_ * NPAD + hseg * 16;

    /* MFMA mapping */
    const int lane = tid & 63, wv = tid >> 6;
    const int l15 = lane & 15, kq = lane >> 4;
    const int rb = wv & 1, cbp = wv >> 1;
    const unsigned short* aP  = &Pl[rb * 16 + l15][kq * 8];
    const unsigned short* bP0 = &hTl[cbp * 32 + l15][kq * 8];
    const unsigned short* bP1 = bP0 + 16 * (TJ + 8);

    facc accA = {0.f, 0.f, 0.f, 0.f}, accB = {0.f, 0.f, 0.f, 0.f};
    float denacc = 0.0f;

    const float4 z4 = make_float4(0.f, 0.f, 0.f, 0.f);
    float4 pa0 = z4, pa1 = z4, pm0 = z4, pm1 = z4, pt0 = z4, pt1 = z4;
    uint4 ph0 = make_uint4(0,0,0,0), ph1 = make_uint4(0,0,0,0);

    auto prefetch = [&](int tile) {
        const int j0 = tile * TJ;
        ph0 = *(const uint4*)(hsrc + j0);
        ph1 = *(const uint4*)(hsrc + j0 + 8);
        const int jl = j0 + (jc << 3);
        if (rowok && jl + 7 < Nn) {
            pa0 = *(const float4*)(aRow + jl); pa1 = *(const float4*)(aRow + jl + 4);
            pm0 = *(const float4*)(mRow + jl); pm1 = *(const float4*)(mRow + jl + 4);
            pt0 = *(const float4*)(tv   + jl); pt1 = *(const float4*)(tv   + jl + 4);
        } else {
            pa0 = pa1 = pm0 = pm1 = pt0 = pt1 = z4;
            if (rowok) {
                #define LD1(dst, base, off) if ((jl + (off)) < Nn) dst = (base)[jl + (off)]
                LD1(pa0.x, aRow, 0); LD1(pa0.y, aRow, 1); LD1(pa0.z, aRow, 2); LD1(pa0.w, aRow, 3);
                LD1(pa1.x, aRow, 4); LD1(pa1.y, aRow, 5); LD1(pa1.z, aRow, 6); LD1(pa1.w, aRow, 7);
                LD1(pm0.x, mRow, 0); LD1(pm0.y, mRow, 1); LD1(pm0.z, mRow, 2); LD1(pm0.w, mRow, 3);
                LD1(pm1.x, mRow, 4); LD1(pm1.y, mRow, 5); LD1(pm1.z, mRow, 6); LD1(pm1.w, mRow, 7);
                LD1(pt0.x, tv,   0); LD1(pt0.y, tv,   1); LD1(pt0.z, tv,   2); LD1(pt0.w, tv,   3);
                LD1(pt1.x, tv,   4); LD1(pt1.y, tv,   5); LD1(pt1.z, tv,   6); LD1(pt1.w, tv,   7);
                #undef LD1
            }
        }
    };

    #define PC(dst, av, mv, tvv) { \
        float e_ = (si + (tvv)) * (mv); \
        float l_ = fmaxf(e_, ALPHA * e_); \
        dst = ((av) > 0.0f) ? exp2f(fmaf(l_, LOG2E, -mc)) : 0.0f; }

    prefetch(tlo);
    for (int tile = tlo; tile < thi; ++tile) {
        __syncthreads();   /* previous MFMA phase done reading LDS */

        *(uint4*)&hTl[hc_][hseg * 16]     = ph0;
        *(uint4*)&hTl[hc_][hseg * 16 + 8] = ph1;

        float4 p40, p41;
        PC(p40.x, pa0.x, pm0.x, pt0.x); PC(p40.y, pa0.y, pm0.y, pt0.y);
        PC(p40.z, pa0.z, pm0.z, pt0.z); PC(p40.w, pa0.w, pm0.w, pt0.w);
        PC(p41.x, pa1.x, pm1.x, pt1.x); PC(p41.y, pa1.y, pm1.y, pt1.y);
        PC(p41.z, pa1.z, pm1.z, pt1.z); PC(p41.w, pa1.w, pm1.w, pt1.w);
        denacc += ((p40.x + p40.y) + (p40.z + p40.w)) + ((p41.x + p41.y) + (p41.z + p41.w));

        uint4 pw;
        pw.x = pk2(p40.x, p40.y); pw.y = pk2(p40.z, p40.w);
        pw.z = pk2(p41.x, p41.y); pw.w = pk2(p41.z, p41.w);
        *(uint4*)&Pl[rr][jc << 3] = pw;

        __syncthreads();   /* staging visible */

        if (tile + 1 < thi) prefetch(tile + 1);   /* HBM loads fly under MFMA */

        #pragma unroll
        for (int k0 = 0; k0 < TJ; k0 += 32) {
            const bfrag af = *(const bfrag*)(aP  + k0);
            const bfrag b0 = *(const bfrag*)(bP0 + k0);
            const bfrag b1 = *(const bfrag*)(bP1 + k0);
            accA = __builtin_amdgcn_mfma_f32_16x16x32_bf16(af, b0, accA, 0, 0, 0);
            accB = __builtin_amdgcn_mfma_f32_16x16x32_bf16(af, b1, accB, 0, 0, 0);
        }
    }
    #undef PC

    /* denominator: reduce the 8 jc-lanes of each row, plain store per y-part */
    float d = denacc;
    d += __shfl_xor(d, 1); d += __shfl_xor(d, 2); d += __shfl_xor(d, 4);
    if (rowok && jc == 0) den_part[blockIdx.y * Nn + prow] = d;

    /* C/D layout (16x16x32): col = lane&15, row = (lane>>4)*4 + reg */
    float* hp = hp_part + (size_t)blockIdx.y * (Nn * OUTF);
    const int orow = i0 + rb * 16 + (kq << 2);
    const int oc   = cbp * 32 + l15;
    #pragma unroll
    for (int r = 0; r < 4; ++r) {
        if (orow + r < Nn) {
            hp[(orow + r) * OUTF + oc]      = accA[r];
            hp[(orow + r) * OUTF + oc + 16] = accB[r];
        }
    }
}

/* ---- kernel 4: sum YS parts, normalize, ELU -> d_out ---- */
__global__ __launch_bounds__(256) void finalize_kernel(
    const float* __restrict__ dp, const float* __restrict__ hp,
    float* __restrict__ out)
{
    const int idx = blockIdx.x * 256 + threadIdx.x;
    const int S = Nn * OUTF;
    const int row = idx >> 6;
    float num = 0.0f, den = 0.0f;
    #pragma unroll
    for (int y = 0; y < YS; ++y) {
        num += hp[(size_t)y * S + idx];
        den += dp[y * Nn + row];
    }
    const float v = num / den;
    out[idx] = (v > 0.0f) ? v : expm1f(v);
}

extern "C" void kernel_launch(void* const* d_in, const int* in_sizes, int n_in,
                              void* d_out, int out_size, void* d_ws, size_t ws_size,
                              hipStream_t stream) {
    const float* x        = (const float*)d_in[0];
    const float* adj      = (const float*)d_in[1];
    const float* Mm       = (const float*)d_in[2];
    const float* W        = (const float*)d_in[3];
    const float* a_self   = (const float*)d_in[4];
    const float* a_neighs = (const float*)d_in[5];

    float* out  = (float*)d_out;
    float* ws   = (float*)d_ws;
    float* s    = ws + WS_S;
    float* t    = ws + WS_T;
    float* tmax = ws + WS_TMAX;
    float* denp = ws + WS_DEN;
    float* hpp  = ws + WS_HP;
    unsigned short* hbfT = (unsigned short*)(ws + WS_HBT);

    hgemm_kernel<<<Nn / 16, 256, 0, stream>>>(x, W, a_self, a_neighs, hbfT, s, t);
    tmax_kernel<<<1, 1024, 0, stream>>>(t, tmax);
    gat_main_kernel<<<dim3((Nn + TI - 1) / TI, YS), 256, 0, stream>>>(
        adj, Mm, hbfT, s, t, tmax, denp, hpp);
    finalize_kernel<<<(Nn * OUTF) / 256, 256, 0, stream>>>(denp, hpp, out);
}